// Round 1
// baseline (1039.154 us; speedup 1.0000x reference)
//
#include <hip/hip_runtime.h>

#define N_NODES 50000
#define N_EDGES 1600000
#define HID     128
#define N_GRAPHS 64

// workspace layout (in 4-byte words)
#define WS_DEG   0u        // int[50000]
#define WS_CUR   50000u    // int[50000]
#define WS_CNT   100000u   // int[64]
#define WS_GSUM  100064u   // float[8192]
#define WS_ZERO_WORDS 108256u  // deg+cursor+cnt+gsum zeroed via memset
#define WS_BSUM  108256u   // int[256]
#define WS_BOFF  108512u   // int[256]
#define WS_OFFS  108768u   // int[50000]
#define WS_INVD  158768u   // float[50000]
#define WS_CSR   208768u   // int[1600000]
#define WS_AGG   1808768u  // float[6400000]
#define WS_END   8208768u  // 32.8 MB total

// ---------------- CSR build ----------------

__global__ __launch_bounds__(256) void k_count(const int* __restrict__ ei, int* __restrict__ deg) {
    int e = blockIdx.x * 256 + threadIdx.x;
    if (e >= N_EDGES) return;
    int d = ei[N_EDGES + e];
    atomicAdd(&deg[d], 1);
}

__global__ __launch_bounds__(256) void k_blockreduce(const int* __restrict__ deg, int* __restrict__ bsum) {
    __shared__ int s[256];
    int i = blockIdx.x * 256 + threadIdx.x;
    s[threadIdx.x] = (i < N_NODES) ? deg[i] : 0;
    __syncthreads();
    for (int d = 128; d > 0; d >>= 1) {
        if (threadIdx.x < d) s[threadIdx.x] += s[threadIdx.x + d];
        __syncthreads();
    }
    if (threadIdx.x == 0) bsum[blockIdx.x] = s[0];
}

__global__ __launch_bounds__(256) void k_scanblocks(const int* __restrict__ bsum, int* __restrict__ boff, int nb) {
    __shared__ int s[256];
    int t = threadIdx.x;
    int v = (t < nb) ? bsum[t] : 0;
    s[t] = v;
    __syncthreads();
    for (int d = 1; d < 256; d <<= 1) {
        int add = (t >= d) ? s[t - d] : 0;
        __syncthreads();
        s[t] += add;
        __syncthreads();
    }
    if (t < nb) boff[t] = s[t] - v;   // exclusive
}

__global__ __launch_bounds__(256) void k_offsets(const int* __restrict__ deg, const int* __restrict__ boff,
                                                 int* __restrict__ offs, float* __restrict__ invdeg) {
    __shared__ int s[256];
    int b = blockIdx.x, t = threadIdx.x;
    int i = b * 256 + t;
    int v = (i < N_NODES) ? deg[i] : 0;
    s[t] = v;
    __syncthreads();
    for (int d = 1; d < 256; d <<= 1) {
        int add = (t >= d) ? s[t - d] : 0;
        __syncthreads();
        s[t] += add;
        __syncthreads();
    }
    if (i < N_NODES) {
        offs[i] = boff[b] + s[t] - v;   // exclusive global offset
        invdeg[i] = 1.0f / fmaxf((float)v, 1.0f);
    }
}

__global__ __launch_bounds__(256) void k_fill(const int* __restrict__ ei, const int* __restrict__ offs,
                                              int* __restrict__ cursor, int* __restrict__ csr) {
    int e = blockIdx.x * 256 + threadIdx.x;
    if (e >= N_EDGES) return;
    int s = ei[e];
    int d = ei[N_EDGES + e];
    int p = offs[d] + atomicAdd(&cursor[d], 1);
    csr[p] = s;
}

// ---------------- per-layer: aggregation (one wave per node) ----------------

__global__ __launch_bounds__(256) void k_agg(const float* __restrict__ x, const int* __restrict__ csr,
                                             const int* __restrict__ offs, const int* __restrict__ deg,
                                             const float* __restrict__ invdeg, float* __restrict__ agg) {
    int w = threadIdx.x >> 6;
    int lane = threadIdx.x & 63;
    int node = blockIdx.x * 4 + w;
    if (node >= N_NODES) return;
    int beg = offs[node];
    int dn = deg[node];
    const float* xb = x + lane * 2;
    float a0 = 0.f, a1 = 0.f;
    int j = 0;
    // 4x unroll for memory-level parallelism
    for (; j + 4 <= dn; j += 4) {
        int s0 = csr[beg + j];
        int s1 = csr[beg + j + 1];
        int s2 = csr[beg + j + 2];
        int s3 = csr[beg + j + 3];
        float2 v0 = *(const float2*)(xb + (size_t)s0 * HID);
        float2 v1 = *(const float2*)(xb + (size_t)s1 * HID);
        float2 v2 = *(const float2*)(xb + (size_t)s2 * HID);
        float2 v3 = *(const float2*)(xb + (size_t)s3 * HID);
        a0 += (v0.x + v1.x) + (v2.x + v3.x);
        a1 += (v0.y + v1.y) + (v2.y + v3.y);
    }
    for (; j < dn; ++j) {
        int s0 = csr[beg + j];
        float2 v0 = *(const float2*)(xb + (size_t)s0 * HID);
        a0 += v0.x;
        a1 += v0.y;
    }
    float id = invdeg[node];
    float2 r;
    r.x = a0 * id;
    r.y = a1 * id;
    *(float2*)(agg + (size_t)node * HID + lane * 2) = r;
}

// ---------------- per-layer: fused (agg@Wn + x@Wr + bn) -> LN -> ReLU ----------------
// block = 256 threads; tile = 32 rows x 128 cols; thread microtile 4x4.
// A staged transposed in LDS with stride 36 (16B-aligned float4 reads, no 32-way write conflict).
// H (32x132) aliases A/W LDS for the LayerNorm phase.

__global__ __launch_bounds__(256) void k_gemm_ln(
        const float* __restrict__ agg, const float* __restrict__ xin,
        const float* __restrict__ Wn, const float* __restrict__ Wr,
        const float* __restrict__ bn, const float* __restrict__ gam,
        const float* __restrict__ bet, float* __restrict__ xout) {
    __shared__ float smem[32 * 36 + 32 * 128];   // 5248 floats = 21 KB
    float* A_lds = smem;            // [k][r] stride 36
    float* W_lds = smem + 32 * 36;  // [k][c] stride 128
    float* H = smem;                // [r][c] stride 132, aliases (4224 <= 5248)

    const int t = threadIdx.x;
    const int tx = t & 31;   // col group: cols tx*4 .. tx*4+3
    const int ty = t >> 5;   // row group: rows ty*4 .. ty*4+3
    const int row0 = blockIdx.x * 32;

    float acc[4][4];
#pragma unroll
    for (int i = 0; i < 4; i++)
#pragma unroll
        for (int j = 0; j < 4; j++) acc[i][j] = 0.f;

    for (int pass = 0; pass < 2; ++pass) {
        const float* A = pass ? xin : agg;
        const float* W = pass ? Wr : Wn;
        for (int k0 = 0; k0 < HID; k0 += 32) {
            __syncthreads();
            {   // stage A transposed: threads: kk = t&31, rbase = t>>5 (+i*8)
                int kk = t & 31;
                int rb = t >> 5;
#pragma unroll
                for (int i = 0; i < 4; i++) {
                    int r = rb + i * 8;
                    int gr = row0 + r;
                    A_lds[kk * 36 + r] = (gr < N_NODES) ? A[(size_t)gr * HID + k0 + kk] : 0.f;
                }
            }
            {   // stage W: 32x128 = 4096 elems, 16 per thread, coalesced
#pragma unroll
                for (int i = 0; i < 16; i++) {
                    int idx = t + i * 256;
                    int kk = idx >> 7;
                    int c = idx & 127;
                    W_lds[idx] = W[(size_t)(k0 + kk) * HID + c];
                }
            }
            __syncthreads();
#pragma unroll
            for (int k = 0; k < 32; k++) {
                float4 a4 = *(const float4*)&A_lds[k * 36 + ty * 4];
                float4 w4 = *(const float4*)&W_lds[(k << 7) + tx * 4];
                float av[4] = {a4.x, a4.y, a4.z, a4.w};
                float wv[4] = {w4.x, w4.y, w4.z, w4.w};
#pragma unroll
                for (int i = 0; i < 4; i++)
#pragma unroll
                    for (int j = 0; j < 4; j++) acc[i][j] = fmaf(av[i], wv[j], acc[i][j]);
            }
        }
    }

    // epilogue: bias -> H (LDS) -> LayerNorm -> ReLU -> store
    __syncthreads();
    float4 b4 = *(const float4*)&bn[tx * 4];
#pragma unroll
    for (int i = 0; i < 4; i++) {
        float4 h4;
        h4.x = acc[i][0] + b4.x;
        h4.y = acc[i][1] + b4.y;
        h4.z = acc[i][2] + b4.z;
        h4.w = acc[i][3] + b4.w;
        *(float4*)&H[(ty * 4 + i) * 132 + tx * 4] = h4;
    }
    __syncthreads();

    int row = t >> 3;    // 0..31
    int sub = t & 7;     // 8 threads per row, 16 cols each
    const float* hr = &H[row * 132 + sub * 16];
    float v[16];
    float s = 0.f, s2 = 0.f;
#pragma unroll
    for (int i = 0; i < 16; i++) {
        v[i] = hr[i];
        s += v[i];
        s2 += v[i] * v[i];
    }
#pragma unroll
    for (int m = 1; m < 8; m <<= 1) {
        s += __shfl_xor(s, m);
        s2 += __shfl_xor(s2, m);
    }
    float mean = s * (1.f / 128.f);
    float var = s2 * (1.f / 128.f) - mean * mean;
    float rstd = rsqrtf(var + 1e-5f);
    int gr = row0 + row;
    if (gr < N_NODES) {
        int cb = sub * 16;
#pragma unroll
        for (int i = 0; i < 16; i++) {
            int c = cb + i;
            float o = (v[i] - mean) * rstd * gam[c] + bet[c];
            xout[(size_t)gr * HID + c] = fmaxf(o, 0.f);
        }
    }
}

// ---------------- graph mean-pool ----------------

__global__ __launch_bounds__(256) void k_pool(const float* __restrict__ xf, const int* __restrict__ batch,
                                              float* __restrict__ gsum, int* __restrict__ cnt) {
    int i = blockIdx.x * 256 + threadIdx.x;
    if (i >= N_NODES * HID) return;
    int node = i >> 7;
    int c = i & 127;
    int g = batch[node];
    atomicAdd(&gsum[(g << 7) + c], xf[i]);
    if (c == 0) atomicAdd(&cnt[g], 1);
}

__global__ __launch_bounds__(256) void k_pool_final(const float* __restrict__ gsum, const int* __restrict__ cnt,
                                                    float* __restrict__ out) {
    int i = blockIdx.x * 256 + threadIdx.x;
    if (i >= N_GRAPHS * HID) return;
    int g = i >> 7;
    float c = (float)cnt[g];
    out[i] = gsum[i] / fmaxf(c, 1.f);
}

extern "C" void kernel_launch(void* const* d_in, const int* in_sizes, int n_in,
                              void* d_out, int out_size, void* d_ws, size_t ws_size,
                              hipStream_t stream) {
    const float* x0 = (const float*)d_in[0];
    const float* Wn = (const float*)d_in[1];
    const float* bn = (const float*)d_in[2];
    const float* Wr = (const float*)d_in[3];
    const float* gam = (const float*)d_in[4];
    const float* bet = (const float*)d_in[5];
    const int* ei = (const int*)d_in[6];
    const int* batch = (const int*)d_in[7];

    float* out = (float*)d_out;                 // [0,8192): graph_emb ; [8192,...): node_emb
    float* node_out = out + N_GRAPHS * HID;

    unsigned* ws = (unsigned*)d_ws;
    int* deg = (int*)(ws + WS_DEG);
    int* cursor = (int*)(ws + WS_CUR);
    int* cnt = (int*)(ws + WS_CNT);
    float* gsum = (float*)(ws + WS_GSUM);
    int* bsum = (int*)(ws + WS_BSUM);
    int* boff = (int*)(ws + WS_BOFF);
    int* offs = (int*)(ws + WS_OFFS);
    float* invdeg = (float*)(ws + WS_INVD);
    int* csr = (int*)(ws + WS_CSR);
    float* agg = (float*)(ws + WS_AGG);

    // zero deg/cursor/cnt/gsum (ws is re-poisoned 0xAA before every call)
    hipMemsetAsync(d_ws, 0, WS_ZERO_WORDS * 4, stream);

    const int eb = (N_EDGES + 255) / 256;          // 6250
    const int nb = (N_NODES + 255) / 256;          // 196
    k_count<<<eb, 256, 0, stream>>>(ei, deg);
    k_blockreduce<<<nb, 256, 0, stream>>>(deg, bsum);
    k_scanblocks<<<1, 256, 0, stream>>>(bsum, boff, nb);
    k_offsets<<<nb, 256, 0, stream>>>(deg, boff, offs, invdeg);
    k_fill<<<eb, 256, 0, stream>>>(ei, offs, cursor, csr);

    const int ab = N_NODES / 4;                    // 12500 (divides exactly)
    const int gb = (N_NODES + 31) / 32;            // 1563

    // layer 0: x = d_in.x -> node_out ; layers 1,2: in-place on node_out
    const float* xcur = x0;
    for (int l = 0; l < 3; ++l) {
        k_agg<<<ab, 256, 0, stream>>>(xcur, csr, offs, deg, invdeg, agg);
        k_gemm_ln<<<gb, 256, 0, stream>>>(agg, xcur,
                                          Wn + (size_t)l * HID * HID, Wr + (size_t)l * HID * HID,
                                          bn + (size_t)l * HID, gam + (size_t)l * HID,
                                          bet + (size_t)l * HID, node_out);
        xcur = node_out;
    }

    k_pool<<<(N_NODES * HID) / 256, 256, 0, stream>>>(node_out, batch, gsum, cnt);
    k_pool_final<<<(N_GRAPHS * HID) / 256, 256, 0, stream>>>(gsum, cnt, out);
}

// Round 2
// 807.188 us; speedup vs baseline: 1.2874x; 1.2874x over previous
//
#include <hip/hip_runtime.h>

#define N_NODES 50000
#define N_EDGES 1600000
#define HID     128
#define N_GRAPHS 64

// workspace layout (in 4-byte words)
#define WS_DEG   0u        // int[50000]
#define WS_CUR   50000u    // int[50000]
#define WS_ZERO_WORDS 100000u  // deg+cursor zeroed via memset
#define WS_BSUM  100000u   // int[256]
#define WS_BOFF  100256u   // int[256]
#define WS_OFFS  100512u   // int[50000]
#define WS_INVD  150512u   // float[50000]
#define WS_CSR   200512u   // int[1600000]
#define WS_AGG   1800512u  // float[6400000]
#define WS_END   8200512u  // 32.8 MB total

// ---------------- CSR build ----------------

__global__ __launch_bounds__(256) void k_count(const int* __restrict__ ei, int* __restrict__ deg) {
    int e = blockIdx.x * 256 + threadIdx.x;
    if (e >= N_EDGES) return;
    int d = ei[N_EDGES + e];
    atomicAdd(&deg[d], 1);
}

__global__ __launch_bounds__(256) void k_blockreduce(const int* __restrict__ deg, int* __restrict__ bsum) {
    __shared__ int s[256];
    int i = blockIdx.x * 256 + threadIdx.x;
    s[threadIdx.x] = (i < N_NODES) ? deg[i] : 0;
    __syncthreads();
    for (int d = 128; d > 0; d >>= 1) {
        if (threadIdx.x < d) s[threadIdx.x] += s[threadIdx.x + d];
        __syncthreads();
    }
    if (threadIdx.x == 0) bsum[blockIdx.x] = s[0];
}

__global__ __launch_bounds__(256) void k_scanblocks(const int* __restrict__ bsum, int* __restrict__ boff, int nb) {
    __shared__ int s[256];
    int t = threadIdx.x;
    int v = (t < nb) ? bsum[t] : 0;
    s[t] = v;
    __syncthreads();
    for (int d = 1; d < 256; d <<= 1) {
        int add = (t >= d) ? s[t - d] : 0;
        __syncthreads();
        s[t] += add;
        __syncthreads();
    }
    if (t < nb) boff[t] = s[t] - v;   // exclusive
}

__global__ __launch_bounds__(256) void k_offsets(const int* __restrict__ deg, const int* __restrict__ boff,
                                                 int* __restrict__ offs, float* __restrict__ invdeg) {
    __shared__ int s[256];
    int b = blockIdx.x, t = threadIdx.x;
    int i = b * 256 + t;
    int v = (i < N_NODES) ? deg[i] : 0;
    s[t] = v;
    __syncthreads();
    for (int d = 1; d < 256; d <<= 1) {
        int add = (t >= d) ? s[t - d] : 0;
        __syncthreads();
        s[t] += add;
        __syncthreads();
    }
    if (i < N_NODES) {
        offs[i] = boff[b] + s[t] - v;   // exclusive global offset
        invdeg[i] = 1.0f / fmaxf((float)v, 1.0f);
    }
}

__global__ __launch_bounds__(256) void k_fill(const int* __restrict__ ei, const int* __restrict__ offs,
                                              int* __restrict__ cursor, int* __restrict__ csr) {
    int e = blockIdx.x * 256 + threadIdx.x;
    if (e >= N_EDGES) return;
    int s = ei[e];
    int d = ei[N_EDGES + e];
    int p = offs[d] + atomicAdd(&cursor[d], 1);
    csr[p] = s;
}

// ---------------- per-layer: aggregation (one wave per node) ----------------

__global__ __launch_bounds__(256) void k_agg(const float* __restrict__ x, const int* __restrict__ csr,
                                             const int* __restrict__ offs, const int* __restrict__ deg,
                                             const float* __restrict__ invdeg, float* __restrict__ agg) {
    int w = threadIdx.x >> 6;
    int lane = threadIdx.x & 63;
    int node = blockIdx.x * 4 + w;
    if (node >= N_NODES) return;
    int beg = offs[node];
    int dn = deg[node];
    const float* xb = x + lane * 2;
    float a0 = 0.f, a1 = 0.f;
    int j = 0;
    // 4x unroll for memory-level parallelism
    for (; j + 4 <= dn; j += 4) {
        int s0 = csr[beg + j];
        int s1 = csr[beg + j + 1];
        int s2 = csr[beg + j + 2];
        int s3 = csr[beg + j + 3];
        float2 v0 = *(const float2*)(xb + (size_t)s0 * HID);
        float2 v1 = *(const float2*)(xb + (size_t)s1 * HID);
        float2 v2 = *(const float2*)(xb + (size_t)s2 * HID);
        float2 v3 = *(const float2*)(xb + (size_t)s3 * HID);
        a0 += (v0.x + v1.x) + (v2.x + v3.x);
        a1 += (v0.y + v1.y) + (v2.y + v3.y);
    }
    for (; j < dn; ++j) {
        int s0 = csr[beg + j];
        float2 v0 = *(const float2*)(xb + (size_t)s0 * HID);
        a0 += v0.x;
        a1 += v0.y;
    }
    float id = invdeg[node];
    float2 r;
    r.x = a0 * id;
    r.y = a1 * id;
    *(float2*)(agg + (size_t)node * HID + lane * 2) = r;
}

// ---------------- per-layer: fused (agg@Wn + x@Wr + bn) -> LN -> ReLU ----------------
// block = 256 threads; tile = 32 rows x 128 cols; thread microtile 4x4.
// A staged transposed in LDS with stride 36 (16B-aligned float4 reads, no 32-way write conflict).
// H (32x132) aliases A/W LDS for the LayerNorm phase.

__global__ __launch_bounds__(256) void k_gemm_ln(
        const float* __restrict__ agg, const float* __restrict__ xin,
        const float* __restrict__ Wn, const float* __restrict__ Wr,
        const float* __restrict__ bn, const float* __restrict__ gam,
        const float* __restrict__ bet, float* __restrict__ xout) {
    __shared__ float smem[32 * 36 + 32 * 128];   // 5248 floats = 21 KB
    float* A_lds = smem;            // [k][r] stride 36
    float* W_lds = smem + 32 * 36;  // [k][c] stride 128
    float* H = smem;                // [r][c] stride 132, aliases (4224 <= 5248)

    const int t = threadIdx.x;
    const int tx = t & 31;   // col group: cols tx*4 .. tx*4+3
    const int ty = t >> 5;   // row group: rows ty*4 .. ty*4+3
    const int row0 = blockIdx.x * 32;

    float acc[4][4];
#pragma unroll
    for (int i = 0; i < 4; i++)
#pragma unroll
        for (int j = 0; j < 4; j++) acc[i][j] = 0.f;

    for (int pass = 0; pass < 2; ++pass) {
        const float* A = pass ? xin : agg;
        const float* W = pass ? Wr : Wn;
        for (int k0 = 0; k0 < HID; k0 += 32) {
            __syncthreads();
            {   // stage A transposed: threads: kk = t&31, rbase = t>>5 (+i*8)
                int kk = t & 31;
                int rb = t >> 5;
#pragma unroll
                for (int i = 0; i < 4; i++) {
                    int r = rb + i * 8;
                    int gr = row0 + r;
                    A_lds[kk * 36 + r] = (gr < N_NODES) ? A[(size_t)gr * HID + k0 + kk] : 0.f;
                }
            }
            {   // stage W: 32x128 = 4096 elems, 16 per thread, coalesced
#pragma unroll
                for (int i = 0; i < 16; i++) {
                    int idx = t + i * 256;
                    int kk = idx >> 7;
                    int c = idx & 127;
                    W_lds[idx] = W[(size_t)(k0 + kk) * HID + c];
                }
            }
            __syncthreads();
#pragma unroll
            for (int k = 0; k < 32; k++) {
                float4 a4 = *(const float4*)&A_lds[k * 36 + ty * 4];
                float4 w4 = *(const float4*)&W_lds[(k << 7) + tx * 4];
                float av[4] = {a4.x, a4.y, a4.z, a4.w};
                float wv[4] = {w4.x, w4.y, w4.z, w4.w};
#pragma unroll
                for (int i = 0; i < 4; i++)
#pragma unroll
                    for (int j = 0; j < 4; j++) acc[i][j] = fmaf(av[i], wv[j], acc[i][j]);
            }
        }
    }

    // epilogue: bias -> H (LDS) -> LayerNorm -> ReLU -> store
    __syncthreads();
    float4 b4 = *(const float4*)&bn[tx * 4];
#pragma unroll
    for (int i = 0; i < 4; i++) {
        float4 h4;
        h4.x = acc[i][0] + b4.x;
        h4.y = acc[i][1] + b4.y;
        h4.z = acc[i][2] + b4.z;
        h4.w = acc[i][3] + b4.w;
        *(float4*)&H[(ty * 4 + i) * 132 + tx * 4] = h4;
    }
    __syncthreads();

    int row = t >> 3;    // 0..31
    int sub = t & 7;     // 8 threads per row, 16 cols each
    const float* hr = &H[row * 132 + sub * 16];
    float v[16];
    float s = 0.f, s2 = 0.f;
#pragma unroll
    for (int i = 0; i < 16; i++) {
        v[i] = hr[i];
        s += v[i];
        s2 += v[i] * v[i];
    }
#pragma unroll
    for (int m = 1; m < 8; m <<= 1) {
        s += __shfl_xor(s, m);
        s2 += __shfl_xor(s2, m);
    }
    float mean = s * (1.f / 128.f);
    float var = s2 * (1.f / 128.f) - mean * mean;
    float rstd = rsqrtf(var + 1e-5f);
    int gr = row0 + row;
    if (gr < N_NODES) {
        int cb = sub * 16;
#pragma unroll
        for (int i = 0; i < 16; i++) {
            int c = cb + i;
            float o = (v[i] - mean) * rstd * gam[c] + bet[c];
            xout[(size_t)gr * HID + c] = fmaxf(o, 0.f);
        }
    }
}

// ---------------- graph mean-pool: atomic-free segmented reduction ----------------
// batch is sorted -> each graph is a contiguous node range. One block per graph:
// binary-search [beg,end), coalesced float2 reads (threads 0..63 cover one 512B row),
// 4 row-partials combined in LDS. count = end - beg (no atomics anywhere).

__global__ __launch_bounds__(256) void k_pool_seg(const float* __restrict__ xf,
                                                  const int* __restrict__ batch,
                                                  float* __restrict__ out) {
    const int g = blockIdx.x;          // 0..63
    __shared__ int s_beg, s_end;
    if (threadIdx.x == 0) {
        int lo = 0, hi = N_NODES;
        while (lo < hi) { int mid = (lo + hi) >> 1; if (batch[mid] < g) lo = mid + 1; else hi = mid; }
        s_beg = lo;
        lo = 0; hi = N_NODES;
        while (lo < hi) { int mid = (lo + hi) >> 1; if (batch[mid] < g + 1) lo = mid + 1; else hi = mid; }
        s_end = lo;
    }
    __syncthreads();
    const int beg = s_beg, end = s_end;
    const int c2 = (threadIdx.x & 63) * 2;   // column pair
    const int q = threadIdx.x >> 6;          // row group 0..3
    float ax = 0.f, ay = 0.f;
    for (int r = beg + q; r < end; r += 4) {
        float2 v = *(const float2*)&xf[(size_t)r * HID + c2];
        ax += v.x;
        ay += v.y;
    }
    __shared__ float sx[4][64], sy[4][64];
    sx[q][threadIdx.x & 63] = ax;
    sy[q][threadIdx.x & 63] = ay;
    __syncthreads();
    if (q == 0) {
        int l = threadIdx.x & 63;
        float tx = sx[0][l] + sx[1][l] + sx[2][l] + sx[3][l];
        float ty = sy[0][l] + sy[1][l] + sy[2][l] + sy[3][l];
        float inv = 1.f / fmaxf((float)(end - beg), 1.f);
        float2 r;
        r.x = tx * inv;
        r.y = ty * inv;
        *(float2*)&out[(g << 7) + c2] = r;
    }
}

extern "C" void kernel_launch(void* const* d_in, const int* in_sizes, int n_in,
                              void* d_out, int out_size, void* d_ws, size_t ws_size,
                              hipStream_t stream) {
    const float* x0 = (const float*)d_in[0];
    const float* Wn = (const float*)d_in[1];
    const float* bn = (const float*)d_in[2];
    const float* Wr = (const float*)d_in[3];
    const float* gam = (const float*)d_in[4];
    const float* bet = (const float*)d_in[5];
    const int* ei = (const int*)d_in[6];
    const int* batch = (const int*)d_in[7];

    float* out = (float*)d_out;                 // [0,8192): graph_emb ; [8192,...): node_emb
    float* node_out = out + N_GRAPHS * HID;

    unsigned* ws = (unsigned*)d_ws;
    int* deg = (int*)(ws + WS_DEG);
    int* cursor = (int*)(ws + WS_CUR);
    int* bsum = (int*)(ws + WS_BSUM);
    int* boff = (int*)(ws + WS_BOFF);
    int* offs = (int*)(ws + WS_OFFS);
    float* invdeg = (float*)(ws + WS_INVD);
    int* csr = (int*)(ws + WS_CSR);
    float* agg = (float*)(ws + WS_AGG);

    // zero deg/cursor (ws is re-poisoned 0xAA before every call)
    hipMemsetAsync(d_ws, 0, WS_ZERO_WORDS * 4, stream);

    const int eb = (N_EDGES + 255) / 256;          // 6250
    const int nb = (N_NODES + 255) / 256;          // 196
    k_count<<<eb, 256, 0, stream>>>(ei, deg);
    k_blockreduce<<<nb, 256, 0, stream>>>(deg, bsum);
    k_scanblocks<<<1, 256, 0, stream>>>(bsum, boff, nb);
    k_offsets<<<nb, 256, 0, stream>>>(deg, boff, offs, invdeg);
    k_fill<<<eb, 256, 0, stream>>>(ei, offs, cursor, csr);

    const int ab = N_NODES / 4;                    // 12500 (divides exactly)
    const int gb = (N_NODES + 31) / 32;            // 1563

    // layer 0: x = d_in.x -> node_out ; layers 1,2: in-place on node_out
    const float* xcur = x0;
    for (int l = 0; l < 3; ++l) {
        k_agg<<<ab, 256, 0, stream>>>(xcur, csr, offs, deg, invdeg, agg);
        k_gemm_ln<<<gb, 256, 0, stream>>>(agg, xcur,
                                          Wn + (size_t)l * HID * HID, Wr + (size_t)l * HID * HID,
                                          bn + (size_t)l * HID, gam + (size_t)l * HID,
                                          bet + (size_t)l * HID, node_out);
        xcur = node_out;
    }

    k_pool_seg<<<N_GRAPHS, 256, 0, stream>>>(node_out, batch, out);
}

// Round 3
// 685.277 us; speedup vs baseline: 1.5164x; 1.1779x over previous
//
#include <hip/hip_runtime.h>

#define N_NODES 50000
#define N_EDGES 1600000
#define HID     128
#define N_GRAPHS 64
#define FILL_PASSES 8
#define NODES_PER_PASS 6250

// workspace layout (in 4-byte words) — 8.2M words = 32.8 MB total
#define WS_DEG   0u        // int[50000]
#define WS_CUR   50000u    // int[50000]
#define WS_ZERO_WORDS 100000u  // deg+cursor zeroed via memset
#define WS_BSUM  100000u   // int[256]
#define WS_BOFF  100256u   // int[256]
#define WS_OFFS  100512u   // int[50000]
#define WS_INVD  150512u   // float[50000]
#define WS_CSR   200512u   // int[1600000]
#define WS_AGG16 1800512u  // uint[3200000]  (bf16 x2: 50000x128)
#define WS_XB16  5000512u  // uint[3200000]  (bf16 x2: 50000x128)
#define WS_END   8200512u

// ---- bf16 helpers (raw, RN-even pack; fp32 math everywhere) ----
__device__ __forceinline__ float bf_lo(unsigned u) { return __uint_as_float(u << 16); }
__device__ __forceinline__ float bf_hi(unsigned u) { return __uint_as_float(u & 0xffff0000u); }
__device__ __forceinline__ unsigned bf_rn(float f) {
    unsigned u = __float_as_uint(f);
    unsigned r = ((u >> 16) & 1u) + 0x7fffu;
    return (u + r) >> 16;
}
__device__ __forceinline__ unsigned bf_pack(float lo, float hi) {
    return bf_rn(lo) | (bf_rn(hi) << 16);
}

// ---------------- x0 fp32 -> bf16 ----------------
__global__ __launch_bounds__(256) void k_cvt(const float4* __restrict__ x, uint2* __restrict__ o) {
    int i = blockIdx.x * 256 + threadIdx.x;      // 1.6M total
    float4 v = x[i];
    uint2 r;
    r.x = bf_pack(v.x, v.y);
    r.y = bf_pack(v.z, v.w);
    o[i] = r;
}

// ---------------- CSR build ----------------

__global__ __launch_bounds__(256) void k_count(const int* __restrict__ ei, int* __restrict__ deg) {
    int e = blockIdx.x * 256 + threadIdx.x;
    if (e >= N_EDGES) return;
    int d = __builtin_nontemporal_load(ei + N_EDGES + e);
    atomicAdd(&deg[d], 1);
}

__global__ __launch_bounds__(256) void k_blockreduce(const int* __restrict__ deg, int* __restrict__ bsum) {
    __shared__ int s[256];
    int i = blockIdx.x * 256 + threadIdx.x;
    s[threadIdx.x] = (i < N_NODES) ? deg[i] : 0;
    __syncthreads();
    for (int d = 128; d > 0; d >>= 1) {
        if (threadIdx.x < d) s[threadIdx.x] += s[threadIdx.x + d];
        __syncthreads();
    }
    if (threadIdx.x == 0) bsum[blockIdx.x] = s[0];
}

__global__ __launch_bounds__(256) void k_scanblocks(const int* __restrict__ bsum, int* __restrict__ boff, int nb) {
    __shared__ int s[256];
    int t = threadIdx.x;
    int v = (t < nb) ? bsum[t] : 0;
    s[t] = v;
    __syncthreads();
    for (int d = 1; d < 256; d <<= 1) {
        int add = (t >= d) ? s[t - d] : 0;
        __syncthreads();
        s[t] += add;
        __syncthreads();
    }
    if (t < nb) boff[t] = s[t] - v;   // exclusive
}

__global__ __launch_bounds__(256) void k_offsets(const int* __restrict__ deg, const int* __restrict__ boff,
                                                 int* __restrict__ offs, float* __restrict__ invdeg) {
    __shared__ int s[256];
    int b = blockIdx.x, t = threadIdx.x;
    int i = b * 256 + t;
    int v = (i < N_NODES) ? deg[i] : 0;
    s[t] = v;
    __syncthreads();
    for (int d = 1; d < 256; d <<= 1) {
        int add = (t >= d) ? s[t - d] : 0;
        __syncthreads();
        s[t] += add;
        __syncthreads();
    }
    if (i < N_NODES) {
        offs[i] = boff[b] + s[t] - v;   // exclusive global offset
        invdeg[i] = 1.0f / fmaxf((float)v, 1.0f);
    }
}

// Multi-pass fill: pass p handles dst in [p*6250,(p+1)*6250) so the live CSR
// subregion is 800 KB (L2-resident) and every 64B line fills completely
// before eviction (writeback ~6.4 MB total, was 101 MB). nt loads keep the
// 12.8 MB ei stream from evicting dirty CSR lines.
__global__ __launch_bounds__(256) void k_fill_mp(const int* __restrict__ ei, const int* __restrict__ offs,
                                                 int* __restrict__ cursor, int* __restrict__ csr, int pass) {
    int e = blockIdx.x * 256 + threadIdx.x;
    if (e >= N_EDGES) return;
    unsigned d = (unsigned)__builtin_nontemporal_load(ei + N_EDGES + e);
    if (d / NODES_PER_PASS != (unsigned)pass) return;
    int s = __builtin_nontemporal_load(ei + e);
    int p = offs[d] + atomicAdd(&cursor[d], 1);
    csr[p] = s;
}

// ---------------- per-layer: aggregation (one wave per node, bf16 rows) ----------------
// row = 128 bf16 = 64 uints; lane loads 1 uint (2 cols), fp32 accumulate.

__global__ __launch_bounds__(256) void k_agg16(const unsigned* __restrict__ xb, const int* __restrict__ csr,
                                               const int* __restrict__ offs, const int* __restrict__ deg,
                                               const float* __restrict__ invdeg, unsigned* __restrict__ agg) {
    int w = threadIdx.x >> 6;
    int lane = threadIdx.x & 63;
    int node = blockIdx.x * 4 + w;
    int beg = offs[node];
    int dn = deg[node];
    const unsigned* xl = xb + lane;
    float a0 = 0.f, a1 = 0.f;
    int j = 0;
    for (; j + 4 <= dn; j += 4) {   // 4x unroll for memory-level parallelism
        int s0 = csr[beg + j];
        int s1 = csr[beg + j + 1];
        int s2 = csr[beg + j + 2];
        int s3 = csr[beg + j + 3];
        unsigned u0 = xl[(size_t)s0 * 64];
        unsigned u1 = xl[(size_t)s1 * 64];
        unsigned u2 = xl[(size_t)s2 * 64];
        unsigned u3 = xl[(size_t)s3 * 64];
        a0 += (bf_lo(u0) + bf_lo(u1)) + (bf_lo(u2) + bf_lo(u3));
        a1 += (bf_hi(u0) + bf_hi(u1)) + (bf_hi(u2) + bf_hi(u3));
    }
    for (; j < dn; ++j) {
        unsigned u0 = xl[(size_t)csr[beg + j] * 64];
        a0 += bf_lo(u0);
        a1 += bf_hi(u0);
    }
    float id = invdeg[node];
    agg[(size_t)node * 64 + lane] = bf_pack(a0 * id, a1 * id);
}

// ---------------- per-layer: fused (agg@Wn + x@Wr + bn) -> LN -> ReLU ----------------
// A operands are bf16 (converted to fp32 in LDS staging); W/accum fp32.
// Writes fp32 xout (node_emb) AND bf16 xb16 (next layer's gather operand).

__global__ __launch_bounds__(256) void k_gemm_ln(
        const unsigned short* __restrict__ aggb, const unsigned short* __restrict__ xinb,
        const float* __restrict__ Wn, const float* __restrict__ Wr,
        const float* __restrict__ bn, const float* __restrict__ gam,
        const float* __restrict__ bet, float* __restrict__ xout,
        unsigned* __restrict__ b16out) {
    __shared__ float smem[32 * 36 + 32 * 128];   // 5248 floats = 21 KB
    float* A_lds = smem;            // [k][r] stride 36
    float* W_lds = smem + 32 * 36;  // [k][c] stride 128
    float* H = smem;                // [r][c] stride 132, aliases (4224 <= 5248)

    const int t = threadIdx.x;
    const int tx = t & 31;   // col group: cols tx*4 .. tx*4+3
    const int ty = t >> 5;   // row group: rows ty*4 .. ty*4+3
    const int row0 = blockIdx.x * 32;

    float acc[4][4];
#pragma unroll
    for (int i = 0; i < 4; i++)
#pragma unroll
        for (int j = 0; j < 4; j++) acc[i][j] = 0.f;

    for (int pass = 0; pass < 2; ++pass) {
        const unsigned short* A = pass ? xinb : aggb;
        const float* W = pass ? Wr : Wn;
        for (int k0 = 0; k0 < HID; k0 += 32) {
            __syncthreads();
            {   // stage A transposed (bf16 -> fp32): kk = t&31, rbase = t>>5 (+i*8)
                int kk = t & 31;
                int rb = t >> 5;
#pragma unroll
                for (int i = 0; i < 4; i++) {
                    int r = rb + i * 8;
                    int gr = row0 + r;
                    unsigned short raw = (gr < N_NODES) ? A[(size_t)gr * HID + k0 + kk] : (unsigned short)0;
                    A_lds[kk * 36 + r] = __uint_as_float(((unsigned)raw) << 16);
                }
            }
            {   // stage W: 32x128 = 4096 elems, 16 per thread, coalesced
#pragma unroll
                for (int i = 0; i < 16; i++) {
                    int idx = t + i * 256;
                    int kk = idx >> 7;
                    int c = idx & 127;
                    W_lds[idx] = W[(size_t)(k0 + kk) * HID + c];
                }
            }
            __syncthreads();
#pragma unroll
            for (int k = 0; k < 32; k++) {
                float4 a4 = *(const float4*)&A_lds[k * 36 + ty * 4];
                float4 w4 = *(const float4*)&W_lds[(k << 7) + tx * 4];
                float av[4] = {a4.x, a4.y, a4.z, a4.w};
                float wv[4] = {w4.x, w4.y, w4.z, w4.w};
#pragma unroll
                for (int i = 0; i < 4; i++)
#pragma unroll
                    for (int j = 0; j < 4; j++) acc[i][j] = fmaf(av[i], wv[j], acc[i][j]);
            }
        }
    }

    // epilogue: bias -> H (LDS) -> LayerNorm -> ReLU -> store fp32 + bf16
    __syncthreads();
    float4 b4 = *(const float4*)&bn[tx * 4];
#pragma unroll
    for (int i = 0; i < 4; i++) {
        float4 h4;
        h4.x = acc[i][0] + b4.x;
        h4.y = acc[i][1] + b4.y;
        h4.z = acc[i][2] + b4.z;
        h4.w = acc[i][3] + b4.w;
        *(float4*)&H[(ty * 4 + i) * 132 + tx * 4] = h4;
    }
    __syncthreads();

    int row = t >> 3;    // 0..31
    int sub = t & 7;     // 8 threads per row, 16 cols each
    const float* hr = &H[row * 132 + sub * 16];
    float v[16];
    float s = 0.f, s2 = 0.f;
#pragma unroll
    for (int i = 0; i < 16; i++) {
        v[i] = hr[i];
        s += v[i];
        s2 += v[i] * v[i];
    }
#pragma unroll
    for (int m = 1; m < 8; m <<= 1) {
        s += __shfl_xor(s, m);
        s2 += __shfl_xor(s2, m);
    }
    float mean = s * (1.f / 128.f);
    float var = s2 * (1.f / 128.f) - mean * mean;
    float rstd = rsqrtf(var + 1e-5f);
    int gr = row0 + row;
    if (gr < N_NODES) {
        int cb = sub * 16;
        float o[16];
#pragma unroll
        for (int i = 0; i < 16; i++) {
            int c = cb + i;
            o[i] = fmaxf((v[i] - mean) * rstd * gam[c] + bet[c], 0.f);
            xout[(size_t)gr * HID + c] = o[i];
        }
#pragma unroll
        for (int i = 0; i < 16; i += 2)
            b16out[(size_t)gr * 64 + ((cb + i) >> 1)] = bf_pack(o[i], o[i + 1]);
    }
}

// ---------------- graph mean-pool: atomic-free segmented reduction ----------------

__global__ __launch_bounds__(256) void k_pool_seg(const float* __restrict__ xf,
                                                  const int* __restrict__ batch,
                                                  float* __restrict__ out) {
    const int g = blockIdx.x;          // 0..63
    __shared__ int s_beg, s_end;
    if (threadIdx.x == 0) {
        int lo = 0, hi = N_NODES;
        while (lo < hi) { int mid = (lo + hi) >> 1; if (batch[mid] < g) lo = mid + 1; else hi = mid; }
        s_beg = lo;
        lo = 0; hi = N_NODES;
        while (lo < hi) { int mid = (lo + hi) >> 1; if (batch[mid] < g + 1) lo = mid + 1; else hi = mid; }
        s_end = lo;
    }
    __syncthreads();
    const int beg = s_beg, end = s_end;
    const int c2 = (threadIdx.x & 63) * 2;   // column pair
    const int q = threadIdx.x >> 6;          // row group 0..3
    float ax = 0.f, ay = 0.f;
    for (int r = beg + q; r < end; r += 4) {
        float2 v = *(const float2*)&xf[(size_t)r * HID + c2];
        ax += v.x;
        ay += v.y;
    }
    __shared__ float sx[4][64], sy[4][64];
    sx[q][threadIdx.x & 63] = ax;
    sy[q][threadIdx.x & 63] = ay;
    __syncthreads();
    if (q == 0) {
        int l = threadIdx.x & 63;
        float tx = sx[0][l] + sx[1][l] + sx[2][l] + sx[3][l];
        float ty = sy[0][l] + sy[1][l] + sy[2][l] + sy[3][l];
        float inv = 1.f / fmaxf((float)(end - beg), 1.f);
        float2 r;
        r.x = tx * inv;
        r.y = ty * inv;
        *(float2*)&out[(g << 7) + c2] = r;
    }
}

extern "C" void kernel_launch(void* const* d_in, const int* in_sizes, int n_in,
                              void* d_out, int out_size, void* d_ws, size_t ws_size,
                              hipStream_t stream) {
    const float* x0 = (const float*)d_in[0];
    const float* Wn = (const float*)d_in[1];
    const float* bn = (const float*)d_in[2];
    const float* Wr = (const float*)d_in[3];
    const float* gam = (const float*)d_in[4];
    const float* bet = (const float*)d_in[5];
    const int* ei = (const int*)d_in[6];
    const int* batch = (const int*)d_in[7];

    float* out = (float*)d_out;                 // [0,8192): graph_emb ; [8192,...): node_emb
    float* node_out = out + N_GRAPHS * HID;

    unsigned* ws = (unsigned*)d_ws;
    int* deg = (int*)(ws + WS_DEG);
    int* cursor = (int*)(ws + WS_CUR);
    int* bsum = (int*)(ws + WS_BSUM);
    int* boff = (int*)(ws + WS_BOFF);
    int* offs = (int*)(ws + WS_OFFS);
    float* invdeg = (float*)(ws + WS_INVD);
    int* csr = (int*)(ws + WS_CSR);
    unsigned* agg16 = ws + WS_AGG16;
    unsigned* xb16 = ws + WS_XB16;

    // zero deg/cursor (ws is re-poisoned 0xAA before every call)
    hipMemsetAsync(d_ws, 0, WS_ZERO_WORDS * 4, stream);

    const int eb = (N_EDGES + 255) / 256;          // 6250
    const int nb = (N_NODES + 255) / 256;          // 196
    k_cvt<<<(N_NODES * HID / 4) / 256, 256, 0, stream>>>((const float4*)x0, (uint2*)xb16);
    k_count<<<eb, 256, 0, stream>>>(ei, deg);
    k_blockreduce<<<nb, 256, 0, stream>>>(deg, bsum);
    k_scanblocks<<<1, 256, 0, stream>>>(bsum, boff, nb);
    k_offsets<<<nb, 256, 0, stream>>>(deg, boff, offs, invdeg);
    for (int p = 0; p < FILL_PASSES; ++p)
        k_fill_mp<<<eb, 256, 0, stream>>>(ei, offs, cursor, csr, p);

    const int ab = N_NODES / 4;                    // 12500 (divides exactly)
    const int gb = (N_NODES + 31) / 32;            // 1563

    for (int l = 0; l < 3; ++l) {
        k_agg16<<<ab, 256, 0, stream>>>(xb16, csr, offs, deg, invdeg, agg16);
        k_gemm_ln<<<gb, 256, 0, stream>>>((const unsigned short*)agg16, (const unsigned short*)xb16,
                                          Wn + (size_t)l * HID * HID, Wr + (size_t)l * HID * HID,
                                          bn + (size_t)l * HID, gam + (size_t)l * HID,
                                          bet + (size_t)l * HID, node_out, xb16);
    }

    k_pool_seg<<<N_GRAPHS, 256, 0, stream>>>(node_out, batch, out);
}